// Round 5
// baseline (110.747 us; speedup 1.0000x reference)
//
#include <hip/hip_runtime.h>
#include <hip/hip_bf16.h>

#define NB 20000      // batch
#define KN 16         // neighbors
#define D 256
#define KDIM 512      // 2*D
#define MDIM 512      // 2*OUT stacked
#define BN 32         // chunk of batch rows per work item
#define NCHUNK (NB / BN)   // 625
#define LDB 520       // padded comb row (elems); 1040B stride, 16B-aligned

typedef __bf16 bf16x8 __attribute__((ext_vector_type(8)));
typedef float f32x4 __attribute__((ext_vector_type(4)));

__device__ inline unsigned short f2bf(float f) {
    union { float f; unsigned int u; } a; a.f = f;
    unsigned int u = a.u;
    unsigned int r = (u + 0x7FFFu + ((u >> 16) & 1u)) >> 16;   // RNE
    return (unsigned short)r;
}

// --- kernel 1: W1||W2 f32 -> bf16 stacked [512][512]; also resets queue ---
__global__ __launch_bounds__(256) void convW_kernel(
        const float* __restrict__ W1, const float* __restrict__ W2,
        unsigned short* __restrict__ Wc, int* __restrict__ ctr) {
    if (blockIdx.x == 0 && threadIdx.x == 0) *ctr = 0;
    int i = blockIdx.x * 256 + threadIdx.x;          // 65536 float4 chunks
    float4 v = (i < 32768) ? reinterpret_cast<const float4*>(W1)[i]
                           : reinterpret_cast<const float4*>(W2)[i - 32768];
    ushort4 o;
    o.x = f2bf(v.x); o.y = f2bf(v.y); o.z = f2bf(v.z); o.w = f2bf(v.w);
    reinterpret_cast<ushort4*>(Wc)[i] = o;
}

// --- fused kernel: per chunk of 32 batch rows: gather+mean -> LDS, then
//     [512 x 32] GEMM with A read directly from L2-hot Wc. Persistent blocks
//     pull chunks from an atomic queue (output independent of assignment). ---
__global__ __launch_bounds__(256, 2) void fused_kernel(
        const int* __restrict__ nodes, const int* __restrict__ neigh,
        const float* __restrict__ feat, const unsigned short* __restrict__ Wc,
        float* __restrict__ out, int* __restrict__ ctr) {
    __shared__ __align__(16) unsigned short comb[2][BN][LDB];
    __shared__ int sChunk;

    int tid = threadIdx.x;
    int lane = tid & 63;
    int wid = tid >> 6;                      // 4 waves; wave owns m-slice wid*128
    const float4* f4 = reinterpret_cast<const float4*>(feat);  // row = 64 float4

    // ---- gather one chunk into comb[b] (each wave: 8 batch rows) ----
    auto gather_chunk = [&](int chunk, int b) {
        #pragma unroll 1
        for (int r = 0; r < 8; ++r) {
            int bl = wid * 8 + r;
            int bb = chunk * BN + bl;
            int node = nodes[bb];
            int idx[KN];
            #pragma unroll
            for (int k = 0; k < KN; k += 4) {
                int4 q = *reinterpret_cast<const int4*>(&neigh[bb * KN + k]);
                idx[k] = q.x; idx[k + 1] = q.y; idx[k + 2] = q.z; idx[k + 3] = q.w;
            }
            float4 s = f4[(size_t)node * 64 + lane];
            float4 v[KN];
            #pragma unroll
            for (int k = 0; k < KN; ++k)
                v[k] = f4[(size_t)idx[k] * 64 + lane];
            #pragma unroll
            for (int st = 8; st >= 1; st >>= 1)
                #pragma unroll
                for (int k = 0; k < st; ++k) {
                    v[k].x += v[k + st].x; v[k].y += v[k + st].y;
                    v[k].z += v[k + st].z; v[k].w += v[k + st].w;
                }
            const float inv = 1.0f / 16.0f;
            ushort4 sv; sv.x = f2bf(s.x); sv.y = f2bf(s.y);
            sv.z = f2bf(s.z); sv.w = f2bf(s.w);
            ushort4 mv; mv.x = f2bf(v[0].x * inv); mv.y = f2bf(v[0].y * inv);
            mv.z = f2bf(v[0].z * inv); mv.w = f2bf(v[0].w * inv);
            *reinterpret_cast<ushort4*>(&comb[b][bl][lane * 4]) = sv;       // self
            *reinterpret_cast<ushort4*>(&comb[b][bl][D + lane * 4]) = mv;   // mean
        }
    };

    // ---- GEMM one chunk: out[512][nBase..nBase+32) ----
    auto gemm_chunk = [&](int chunk, int b) {
        f32x4 acc[8][2] = {};
        int rl = lane & 15;
        int kq8 = (lane >> 4) * 8;
        #pragma unroll 2
        for (int k0 = 0; k0 < KDIM; k0 += 32) {
            bf16x8 bfrag[2];
            #pragma unroll
            for (int j = 0; j < 2; ++j)
                bfrag[j] = *reinterpret_cast<const bf16x8*>(
                    &comb[b][j * 16 + rl][k0 + kq8]);
            #pragma unroll
            for (int i = 0; i < 8; ++i) {
                bf16x8 afrag = *reinterpret_cast<const bf16x8*>(
                    &Wc[(size_t)(wid * 128 + i * 16 + rl) * KDIM + k0 + kq8]);
                acc[i][0] = __builtin_amdgcn_mfma_f32_16x16x32_bf16(
                    afrag, bfrag[0], acc[i][0], 0, 0, 0);
                acc[i][1] = __builtin_amdgcn_mfma_f32_16x16x32_bf16(
                    afrag, bfrag[1], acc[i][1], 0, 0, 0);
            }
        }
        int col = lane & 15;
        int rq = (lane >> 4) * 4;
        int nBase = chunk * BN;
        #pragma unroll
        for (int i = 0; i < 8; ++i)
            #pragma unroll
            for (int j = 0; j < 2; ++j) {
                int n = nBase + j * 16 + col;
                int mRow = wid * 128 + i * 16 + rq;
                #pragma unroll
                for (int rr = 0; rr < 4; ++rr) {
                    float x = acc[i][j][rr];
                    out[(size_t)(mRow + rr) * NB + n] = x > 0.f ? x : 0.f;
                }
            }
    };

    // ---- persistent loop over the chunk queue ----
    if (tid == 0) sChunk = atomicAdd(ctr, 1);
    __syncthreads();
    int cur = sChunk;
    if (cur >= NCHUNK) return;
    int buf = 0;
    gather_chunk(cur, buf);
    __syncthreads();                          // comb[buf] ready; sChunk consumed

    while (true) {
        if (tid == 0) sChunk = atomicAdd(ctr, 1);
        __syncthreads();
        int nxt = sChunk;
        if (nxt < NCHUNK) gather_chunk(nxt, buf ^ 1);   // issue memory work first
        gemm_chunk(cur, buf);                           // MFMA under gather shadow
        __syncthreads();                      // reads of comb[buf] done; writes vis.
        if (nxt >= NCHUNK) break;
        cur = nxt; buf ^= 1;
    }
}

extern "C" void kernel_launch(void* const* d_in, const int* in_sizes, int n_in,
                              void* d_out, int out_size, void* d_ws, size_t ws_size,
                              hipStream_t stream) {
    const int*   nodes = (const int*)d_in[0];
    const int*   neigh = (const int*)d_in[1];
    const float* feat  = (const float*)d_in[2];
    const float* W1    = (const float*)d_in[3];
    const float* W2    = (const float*)d_in[4];
    float* out = (float*)d_out;

    // ws layout: Wc (512KB) | ctr (4B)
    const size_t WC_BYTES = (size_t)MDIM * KDIM * 2;
    unsigned short* Wc = (unsigned short*)d_ws;
    int* ctr = (int*)((char*)d_ws + WC_BYTES);

    convW_kernel<<<256, 256, 0, stream>>>(W1, W2, Wc, ctr);
    fused_kernel<<<512, 256, 0, stream>>>(nodes, neigh, feat, Wc, out, ctr);
}

// Round 6
// 96.583 us; speedup vs baseline: 1.1466x; 1.1466x over previous
//
#include <hip/hip_runtime.h>
#include <hip/hip_bf16.h>

#define NB 20000      // batch
#define KN 16         // neighbors
#define D 256
#define KDIM 512      // 2*D
#define MDIM 512      // 2*OUT stacked

typedef __bf16 bf16x8 __attribute__((ext_vector_type(8)));
typedef float f32x4 __attribute__((ext_vector_type(4)));

__device__ inline unsigned short f2bf(float f) {
    union { float f; unsigned int u; } a; a.f = f;
    unsigned int u = a.u;
    unsigned int r = (u + 0x7FFFu + ((u >> 16) & 1u)) >> 16;   // RNE
    return (unsigned short)r;
}

__device__ inline void gload_lds16(const void* g, void* l) {
    __builtin_amdgcn_global_load_lds(
        (const __attribute__((address_space(1))) unsigned int*)g,
        (__attribute__((address_space(3))) unsigned int*)l, 16, 0, 0);
}

// --- kernel 1: W1||W2 f32 -> bf16, stacked [512][512] ---
__global__ __launch_bounds__(256) void convW_kernel(
        const float* __restrict__ W1, const float* __restrict__ W2,
        unsigned short* __restrict__ Wc) {
    int i = blockIdx.x * 256 + threadIdx.x;          // 65536 float4 chunks
    float4 v = (i < 32768) ? reinterpret_cast<const float4*>(W1)[i]
                           : reinterpret_cast<const float4*>(W2)[i - 32768];
    ushort4 o;
    o.x = f2bf(v.x); o.y = f2bf(v.y); o.z = f2bf(v.z); o.w = f2bf(v.w);
    reinterpret_cast<ushort4*>(Wc)[i] = o;
}

// --- kernel 2: gather + mean aggregate (R2-exact, 62us known) ---
__global__ __launch_bounds__(256) void agg_kernel(
        const int* __restrict__ nodes, const int* __restrict__ neigh,
        const float* __restrict__ feat, unsigned short* __restrict__ comb) {
    int w = threadIdx.x >> 6;
    int lane = threadIdx.x & 63;
    int b = blockIdx.x * 4 + w;                      // grid = 5000 -> b < 20000
    const float4* f4 = reinterpret_cast<const float4*>(feat);  // row = 64 float4

    int node = nodes[b];
    float4 s = f4[(size_t)node * 64 + lane];

    float4 m; m.x = 0.f; m.y = 0.f; m.z = 0.f; m.w = 0.f;
    #pragma unroll
    for (int k = 0; k < KN; ++k) {
        int idx = neigh[b * KN + k];
        float4 v = f4[(size_t)idx * 64 + lane];
        m.x += v.x; m.y += v.y; m.z += v.z; m.w += v.w;
    }
    const float inv = 1.0f / 16.0f;

    ushort4 sv; sv.x = f2bf(s.x); sv.y = f2bf(s.y); sv.z = f2bf(s.z); sv.w = f2bf(s.w);
    ushort4 mv; mv.x = f2bf(m.x * inv); mv.y = f2bf(m.y * inv);
    mv.z = f2bf(m.z * inv); mv.w = f2bf(m.w * inv);

    unsigned short* row = comb + (size_t)b * KDIM;
    *reinterpret_cast<ushort4*>(row + lane * 4) = sv;          // self  [0,256)
    *reinterpret_cast<ushort4*>(row + D + lane * 4) = mv;      // mean  [256,512)
}

// --- kernel 3: BM=256 x BN=128, BK=64, global_load_lds staging, f32 out ---
#define GBM 256
#define GBN 128
#define GBK 64

__global__ __launch_bounds__(512) void gemm2_kernel(
        const unsigned short* __restrict__ Wc,    // [512][512] bf16
        const unsigned short* __restrict__ Cb,    // [20000][512] bf16
        float* __restrict__ out) {                // [512][20000] f32
    __shared__ __align__(16) unsigned short As[GBM * GBK];   // 32KB, row-major [256][64]
    __shared__ __align__(16) unsigned short Bs[GBN * GBK];   // 16KB, row-major [128][64]

    int tid = threadIdx.x;
    int lane = tid & 63;
    int wid = tid >> 6;                 // 0..7
    int wm = wid >> 1;                  // 0..3 -> m-slice of 64
    int wn = wid & 1;                   // 0..1 -> n-slice of 64
    int mBase = blockIdx.y * GBM;
    int nBase = blockIdx.x * GBN;

    int rl = lane & 15;
    int kq8 = (lane >> 4) * 8;
    int lrow = lane >> 3;               // 0..7 (row within 8-row staging slab)
    int lcol = (lane & 7) * 8;          // 0..56 (elem col within 64)

    f32x4 acc[4][4] = {};

    for (int kt = 0; kt < KDIM / GBK; ++kt) {
        int k0 = kt * GBK;
        // stage A: 256 rows x 128B = 32 wave-slabs of 1KB; 4 per wave
        #pragma unroll
        for (int i = 0; i < 4; ++i) {
            int q = wid * 4 + i;                          // slab 0..31
            gload_lds16(Wc + (size_t)(mBase + q * 8 + lrow) * KDIM + k0 + lcol,
                        As + q * 512);                    // q*1024 bytes
        }
        // stage B: 128 rows = 16 slabs; 2 per wave (clamp OOB rows to NB-1)
        #pragma unroll
        for (int i = 0; i < 2; ++i) {
            int q = wid * 2 + i;                          // slab 0..15
            int gb = nBase + q * 8 + lrow;
            if (gb > NB - 1) gb = NB - 1;
            gload_lds16(Cb + (size_t)gb * KDIM + k0 + lcol,
                        Bs + q * 512);
        }
        __syncthreads();

        #pragma unroll
        for (int kk = 0; kk < GBK; kk += 32) {
            bf16x8 af[4], bfr[4];
            #pragma unroll
            for (int i = 0; i < 4; ++i)
                af[i] = *reinterpret_cast<const bf16x8*>(
                    &As[(wm * 64 + i * 16 + rl) * GBK + kk + kq8]);
            #pragma unroll
            for (int j = 0; j < 4; ++j)
                bfr[j] = *reinterpret_cast<const bf16x8*>(
                    &Bs[(wn * 64 + j * 16 + rl) * GBK + kk + kq8]);
            #pragma unroll
            for (int i = 0; i < 4; ++i)
                #pragma unroll
                for (int j = 0; j < 4; ++j)
                    acc[i][j] = __builtin_amdgcn_mfma_f32_16x16x32_bf16(
                        af[i], bfr[j], acc[i][j], 0, 0, 0);
        }
        __syncthreads();
    }

    // epilogue: C/D layout col=lane&15, row=(lane>>4)*4+reg (R2-verified)
    int col = lane & 15;
    int rq = (lane >> 4) * 4;
    #pragma unroll
    for (int i = 0; i < 4; ++i) {
        int mRow = mBase + wm * 64 + i * 16 + rq;
        #pragma unroll
        for (int j = 0; j < 4; ++j) {
            int n = nBase + wn * 64 + j * 16 + col;
            if (n < NB) {
                #pragma unroll
                for (int rr = 0; rr < 4; ++rr) {
                    float x = acc[i][j][rr];
                    out[(size_t)(mRow + rr) * NB + n] = x > 0.f ? x : 0.f;
                }
            }
        }
    }
}

extern "C" void kernel_launch(void* const* d_in, const int* in_sizes, int n_in,
                              void* d_out, int out_size, void* d_ws, size_t ws_size,
                              hipStream_t stream) {
    const int*   nodes = (const int*)d_in[0];
    const int*   neigh = (const int*)d_in[1];
    const float* feat  = (const float*)d_in[2];
    const float* W1    = (const float*)d_in[3];
    const float* W2    = (const float*)d_in[4];
    float* out = (float*)d_out;

    // ws layout: Wc (512KB) | comb (20.48MB)
    const size_t WC_BYTES = (size_t)MDIM * KDIM * 2;
    unsigned short* Wc   = (unsigned short*)d_ws;
    unsigned short* comb = (unsigned short*)((char*)d_ws + WC_BYTES);

    convW_kernel<<<256, 256, 0, stream>>>(W1, W2, Wc);
    agg_kernel<<<NB / 4, 256, 0, stream>>>(nodes, neigh, feat, comb);
    gemm2_kernel<<<dim3((NB + GBN - 1) / GBN, MDIM / GBM), 512, 0, stream>>>(Wc, comb, out);
}

// Round 7
// 92.673 us; speedup vs baseline: 1.1950x; 1.0422x over previous
//
#include <hip/hip_runtime.h>
#include <hip/hip_bf16.h>

#define NB 20000      // batch
#define KN 16         // neighbors
#define D 256
#define KDIM 512      // 2*D
#define MDIM 512      // 2*OUT stacked

typedef __bf16 bf16x8 __attribute__((ext_vector_type(8)));
typedef float f32x4 __attribute__((ext_vector_type(4)));

__device__ inline unsigned short f2bf(float f) {
    union { float f; unsigned int u; } a; a.f = f;
    unsigned int u = a.u;
    unsigned int r = (u + 0x7FFFu + ((u >> 16) & 1u)) >> 16;   // RNE
    return (unsigned short)r;
}

// --- kernel 1: W1||W2 f32 -> bf16, stacked [512][512] ---
__global__ __launch_bounds__(256) void convW_kernel(
        const float* __restrict__ W1, const float* __restrict__ W2,
        unsigned short* __restrict__ Wc) {
    int i = blockIdx.x * 256 + threadIdx.x;          // 65536 float4 chunks
    float4 v = (i < 32768) ? reinterpret_cast<const float4*>(W1)[i]
                           : reinterpret_cast<const float4*>(W2)[i - 32768];
    ushort4 o;
    o.x = f2bf(v.x); o.y = f2bf(v.y); o.z = f2bf(v.z); o.w = f2bf(v.w);
    reinterpret_cast<ushort4*>(Wc)[i] = o;
}

// --- kernel 2: gather + mean aggregate (R2-exact, known 62us) ---
__global__ __launch_bounds__(256) void agg_kernel(
        const int* __restrict__ nodes, const int* __restrict__ neigh,
        const float* __restrict__ feat, unsigned short* __restrict__ comb) {
    int w = threadIdx.x >> 6;
    int lane = threadIdx.x & 63;
    int b = blockIdx.x * 4 + w;                      // grid = 5000 -> b < 20000
    const float4* f4 = reinterpret_cast<const float4*>(feat);  // row = 64 float4

    int node = nodes[b];
    float4 s = f4[(size_t)node * 64 + lane];

    float4 m; m.x = 0.f; m.y = 0.f; m.z = 0.f; m.w = 0.f;
    #pragma unroll
    for (int k = 0; k < KN; ++k) {
        int idx = neigh[b * KN + k];
        float4 v = f4[(size_t)idx * 64 + lane];
        m.x += v.x; m.y += v.y; m.z += v.z; m.w += v.w;
    }
    const float inv = 1.0f / 16.0f;

    ushort4 sv; sv.x = f2bf(s.x); sv.y = f2bf(s.y); sv.z = f2bf(s.z); sv.w = f2bf(s.w);
    ushort4 mv; mv.x = f2bf(m.x * inv); mv.y = f2bf(m.y * inv);
    mv.z = f2bf(m.z * inv); mv.w = f2bf(m.w * inv);

    unsigned short* row = comb + (size_t)b * KDIM;
    *reinterpret_cast<ushort4*>(row + lane * 4) = sv;          // self  [0,256)
    *reinterpret_cast<ushort4*>(row + D + lane * 4) = mv;      // mean  [256,512)
}

// --- kernel 3: BM=512 (full M) x BN=80, BK=64; comb read ONCE.
//     grid = 250 blocks = exactly 1/CU. Reg-staged LDS, XOR-swizzled
//     16B chunks (chunk ^= row&7) on write AND read -> <=2-way conflicts. ---
#define GBN 80
#define GBK 64
#define NBLK (NB / GBN)   // 250

__global__ __launch_bounds__(512) void gemm3_kernel(
        const unsigned short* __restrict__ Wc,    // [512][512] bf16
        const unsigned short* __restrict__ Cb,    // [20000][512] bf16
        float* __restrict__ out) {                // [512][20000] f32
    // byte stride per row = GBK*2 = 128B = 8 x 16B chunks
    __shared__ __align__(16) unsigned short As[MDIM * GBK];   // 64KB
    __shared__ __align__(16) unsigned short Bs[GBN * GBK];    // 10KB

    int tid = threadIdx.x;
    int lane = tid & 63;
    int wid = tid >> 6;                 // 0..7 -> m-slice of 64 rows
    int nBase = blockIdx.x * GBN;

    int rl = lane & 15;
    int kq8 = (lane >> 4) * 8;          // 0,8,16,24 (elems)

    f32x4 acc[4][5] = {};

    for (int kt = 0; kt < KDIM / GBK; ++kt) {
        int k0 = kt * GBK;
        // ---- stage A: 512 rows x 8 chunks of 16B; 8 iters, 1 chunk/thread ----
        {
            int ch = tid & 7;                       // chunk within row
            int r0 = tid >> 3;                      // 0..63
            #pragma unroll
            for (int i = 0; i < 8; ++i) {
                int r = r0 + i * 64;
                uint4 v = *reinterpret_cast<const uint4*>(
                    Wc + (size_t)r * KDIM + k0 + ch * 8);
                int dst = ch ^ (r & 7);
                *reinterpret_cast<uint4*>(
                    reinterpret_cast<char*>(As) + r * 128 + dst * 16) = v;
            }
        }
        // ---- stage B: 80 rows x 8 chunks = 640 chunks; 512 + 128 ----
        {
            int c = tid;                            // first 512 chunks
            int r = c >> 3, ch = c & 7;
            uint4 v = *reinterpret_cast<const uint4*>(
                Cb + (size_t)(nBase + r) * KDIM + k0 + ch * 8);
            int dst = ch ^ (r & 7);
            *reinterpret_cast<uint4*>(
                reinterpret_cast<char*>(Bs) + r * 128 + dst * 16) = v;
            if (tid < 128) {
                int c2 = 512 + tid;
                int r2 = c2 >> 3, ch2 = c2 & 7;
                uint4 v2 = *reinterpret_cast<const uint4*>(
                    Cb + (size_t)(nBase + r2) * KDIM + k0 + ch2 * 8);
                int dst2 = ch2 ^ (r2 & 7);
                *reinterpret_cast<uint4*>(
                    reinterpret_cast<char*>(Bs) + r2 * 128 + dst2 * 16) = v2;
            }
        }
        __syncthreads();

        #pragma unroll
        for (int kk = 0; kk < GBK; kk += 32) {
            int j0 = (kk + kq8) >> 3;               // source chunk 0..7
            bf16x8 af[4], bfr[5];
            #pragma unroll
            for (int i = 0; i < 4; ++i) {
                int R = wid * 64 + i * 16 + rl;
                af[i] = *reinterpret_cast<const bf16x8*>(
                    reinterpret_cast<const char*>(As) + R * 128 + (j0 ^ (R & 7)) * 16);
            }
            #pragma unroll
            for (int j = 0; j < 5; ++j) {
                int R = j * 16 + rl;
                bfr[j] = *reinterpret_cast<const bf16x8*>(
                    reinterpret_cast<const char*>(Bs) + R * 128 + (j0 ^ (R & 7)) * 16);
            }
            #pragma unroll
            for (int i = 0; i < 4; ++i)
                #pragma unroll
                for (int j = 0; j < 5; ++j)
                    acc[i][j] = __builtin_amdgcn_mfma_f32_16x16x32_bf16(
                        af[i], bfr[j], acc[i][j], 0, 0, 0);
        }
        __syncthreads();
    }

    // epilogue: C/D layout col=lane&15, row=(lane>>4)*4+reg (R2-verified)
    int col = lane & 15;
    int rq = (lane >> 4) * 4;
    #pragma unroll
    for (int i = 0; i < 4; ++i) {
        int mRow = wid * 64 + i * 16 + rq;
        #pragma unroll
        for (int j = 0; j < 5; ++j) {
            int n = nBase + j * 16 + col;           // exact fit: no bounds check
            #pragma unroll
            for (int rr = 0; rr < 4; ++rr) {
                float x = acc[i][j][rr];
                out[(size_t)(mRow + rr) * NB + n] = x > 0.f ? x : 0.f;
            }
        }
    }
}

extern "C" void kernel_launch(void* const* d_in, const int* in_sizes, int n_in,
                              void* d_out, int out_size, void* d_ws, size_t ws_size,
                              hipStream_t stream) {
    const int*   nodes = (const int*)d_in[0];
    const int*   neigh = (const int*)d_in[1];
    const float* feat  = (const float*)d_in[2];
    const float* W1    = (const float*)d_in[3];
    const float* W2    = (const float*)d_in[4];
    float* out = (float*)d_out;

    // ws layout: Wc (512KB) | comb (20.48MB)
    const size_t WC_BYTES = (size_t)MDIM * KDIM * 2;
    unsigned short* Wc   = (unsigned short*)d_ws;
    unsigned short* comb = (unsigned short*)((char*)d_ws + WC_BYTES);

    convW_kernel<<<256, 256, 0, stream>>>(W1, W2, Wc);
    agg_kernel<<<NB / 4, 256, 0, stream>>>(nodes, neigh, feat, comb);
    gemm3_kernel<<<NBLK, 512, 0, stream>>>(Wc, comb, out);
}

// Round 9
// 88.994 us; speedup vs baseline: 1.2444x; 1.0413x over previous
//
#include <hip/hip_runtime.h>
#include <hip/hip_bf16.h>

#define NB 20000      // batch
#define KN 16         // neighbors
#define D 256
#define KDIM 512      // 2*D
#define MDIM 512      // 2*OUT stacked

typedef __bf16 bf16x8 __attribute__((ext_vector_type(8)));
typedef float f32x4 __attribute__((ext_vector_type(4)));

__device__ inline unsigned short f2bf(float f) {
    union { float f; unsigned int u; } a; a.f = f;
    unsigned int u = a.u;
    unsigned int r = (u + 0x7FFFu + ((u >> 16) & 1u)) >> 16;   // RNE
    return (unsigned short)r;
}

__device__ inline void gload_lds16(const void* g, void* l) {
    __builtin_amdgcn_global_load_lds(
        (const __attribute__((address_space(1))) unsigned int*)g,
        (__attribute__((address_space(3))) unsigned int*)l, 16, 0, 0);
}

// --- kernel 1: W1||W2 f32 -> bf16, stacked [512][512] ---
__global__ __launch_bounds__(256) void convW_kernel(
        const float* __restrict__ W1, const float* __restrict__ W2,
        unsigned short* __restrict__ Wc) {
    int i = blockIdx.x * 256 + threadIdx.x;          // 65536 float4 chunks
    float4 v = (i < 32768) ? reinterpret_cast<const float4*>(W1)[i]
                           : reinterpret_cast<const float4*>(W2)[i - 32768];
    ushort4 o;
    o.x = f2bf(v.x); o.y = f2bf(v.y); o.z = f2bf(v.z); o.w = f2bf(v.w);
    reinterpret_cast<ushort4*>(Wc)[i] = o;
}

// --- kernel 2: gather+mean via ASYNC global_load_lds (17KB in flight/wave).
//     4 waves/block, 17KB LDS each; grid 512 = 2 blocks/CU, 8 waves/CU.
//     Per iter: issue 17 row-gathers async -> LDS, prefetch next indices,
//     vmcnt(0), reduce from LDS, store comb row. ---
#define TOTW 2048     // 512 blocks x 4 waves

__global__ __launch_bounds__(256) void agg3_kernel(
        const int* __restrict__ nodes, const int* __restrict__ neigh,
        const float* __restrict__ feat, unsigned short* __restrict__ comb) {
    __shared__ __align__(16) float stage[4][KN + 1][D];   // 69632 B
    int tid = threadIdx.x;
    int lane = tid & 63;
    int wid = tid >> 6;
    float* buf = &stage[wid][0][0];

    int row = blockIdx.x * 4 + wid;                  // 0..2047
    int node = 0, idx[KN];
    {
        node = nodes[row];
        #pragma unroll
        for (int k = 0; k < KN; k += 4) {
            int4 q = *reinterpret_cast<const int4*>(&neigh[row * KN + k]);
            idx[k] = q.x; idx[k + 1] = q.y; idx[k + 2] = q.z; idx[k + 3] = q.w;
        }
    }

    while (row < NB) {
        // prior iteration's ds_reads fully retired before overwriting buf
        asm volatile("s_waitcnt lgkmcnt(0)" ::: "memory");
        // issue 17 async row-gathers (1KB each; 17KB in flight, 0 VGPR cost)
        gload_lds16(feat + (size_t)node * D + lane * 4, buf);
        #pragma unroll
        for (int k = 0; k < KN; ++k)
            gload_lds16(feat + (size_t)idx[k] * D + lane * 4, buf + (k + 1) * D);

        // prefetch next iteration's indices while gathers are in flight
        int nrow = row + TOTW;
        int nnode = 0, nidx[KN];
        if (nrow < NB) {
            nnode = nodes[nrow];
            #pragma unroll
            for (int k = 0; k < KN; k += 4) {
                int4 q = *reinterpret_cast<const int4*>(&neigh[nrow * KN + k]);
                nidx[k] = q.x; nidx[k + 1] = q.y; nidx[k + 2] = q.z; nidx[k + 3] = q.w;
            }
        }

        asm volatile("s_waitcnt vmcnt(0)" ::: "memory");   // gathers landed
        __builtin_amdgcn_sched_barrier(0);

        // reduce: lane owns 16B column; self = row 0, mean = rows 1..16
        float4 s = *reinterpret_cast<const float4*>(buf + lane * 4);
        float4 m; m.x = 0.f; m.y = 0.f; m.z = 0.f; m.w = 0.f;
        #pragma unroll
        for (int k = 1; k <= KN; ++k) {
            float4 v = *reinterpret_cast<const float4*>(buf + k * D + lane * 4);
            m.x += v.x; m.y += v.y; m.z += v.z; m.w += v.w;
        }
        const float inv = 1.0f / 16.0f;
        ushort4 sv; sv.x = f2bf(s.x); sv.y = f2bf(s.y);
        sv.z = f2bf(s.z); sv.w = f2bf(s.w);
        ushort4 mv; mv.x = f2bf(m.x * inv); mv.y = f2bf(m.y * inv);
        mv.z = f2bf(m.z * inv); mv.w = f2bf(m.w * inv);

        unsigned short* crow = comb + (size_t)row * KDIM;
        *reinterpret_cast<ushort4*>(crow + lane * 4) = sv;        // self
        *reinterpret_cast<ushort4*>(crow + D + lane * 4) = mv;    // mean

        row = nrow; node = nnode;
        #pragma unroll
        for (int k = 0; k < KN; ++k) idx[k] = nidx[k];
    }
}

// --- kernel 3: R2-exact 128x128 GEMM, LDK=40 pad (known-good, ~25us) ---
#define BM 128
#define BN 128
#define LDK 40

__global__ __launch_bounds__(256) void gemm_kernel(
        const unsigned short* __restrict__ Wc,    // [512][512] bf16
        const unsigned short* __restrict__ Cb,    // [20000][512] bf16
        float* __restrict__ out) {                // [512][20000] f32
    __shared__ __align__(16) unsigned short As[BM * LDK];
    __shared__ __align__(16) unsigned short Bs[BN * LDK];

    int tid = threadIdx.x;
    int lane = tid & 63;
    int wid = tid >> 6;
    int wm = wid >> 1, wn = wid & 1;              // 2x2 wave grid, 64x64 each
    int mBase = blockIdx.y * BM;
    int nBase = blockIdx.x * BN;

    f32x4 acc[4][4] = {};

    int srow = tid >> 2;                          // 0..63
    int scol = (tid & 3) * 8;                     // 0,8,16,24

    for (int k0 = 0; k0 < KDIM; k0 += 32) {
        #pragma unroll
        for (int h = 0; h < 2; ++h) {
            int r = srow + h * 64;
            uint4 va = *reinterpret_cast<const uint4*>(
                Wc + (size_t)(mBase + r) * KDIM + k0 + scol);
            *reinterpret_cast<uint4*>(&As[r * LDK + scol]) = va;
            int gb = nBase + r;
            uint4 vb;
            if (gb < NB) vb = *reinterpret_cast<const uint4*>(
                    Cb + (size_t)gb * KDIM + k0 + scol);
            else { vb.x = 0; vb.y = 0; vb.z = 0; vb.w = 0; }
            *reinterpret_cast<uint4*>(&Bs[r * LDK + scol]) = vb;
        }
        __syncthreads();

        int kq = (lane >> 4) * 8;
        int rl = lane & 15;
        bf16x8 af[4], bfr[4];
        #pragma unroll
        for (int i = 0; i < 4; ++i) {
            af[i]  = *reinterpret_cast<const bf16x8*>(&As[(wm * 64 + i * 16 + rl) * LDK + kq]);
            bfr[i] = *reinterpret_cast<const bf16x8*>(&Bs[(wn * 64 + i * 16 + rl) * LDK + kq]);
        }
        #pragma unroll
        for (int i = 0; i < 4; ++i)
            #pragma unroll
            for (int j = 0; j < 4; ++j)
                acc[i][j] = __builtin_amdgcn_mfma_f32_16x16x32_bf16(
                    af[i], bfr[j], acc[i][j], 0, 0, 0);
        __syncthreads();
    }

    // epilogue: C/D layout col=lane&15, row=(lane>>4)*4+reg (verified)
    int col = lane & 15;
    int rq = (lane >> 4) * 4;
    #pragma unroll
    for (int i = 0; i < 4; ++i) {
        int mRow = mBase + wm * 64 + i * 16 + rq;
        #pragma unroll
        for (int j = 0; j < 4; ++j) {
            int n = nBase + wn * 64 + j * 16 + col;
            if (n < NB) {
                #pragma unroll
                for (int rr = 0; rr < 4; ++rr) {
                    float x = acc[i][j][rr];
                    out[(size_t)(mRow + rr) * NB + n] = x > 0.f ? x : 0.f;
                }
            }
        }
    }
}

extern "C" void kernel_launch(void* const* d_in, const int* in_sizes, int n_in,
                              void* d_out, int out_size, void* d_ws, size_t ws_size,
                              hipStream_t stream) {
    const int*   nodes = (const int*)d_in[0];
    const int*   neigh = (const int*)d_in[1];
    const float* feat  = (const float*)d_in[2];
    const float* W1    = (const float*)d_in[3];
    const float* W2    = (const float*)d_in[4];
    float* out = (float*)d_out;

    // ws layout: Wc (512KB) | comb (20.48MB)
    const size_t WC_BYTES = (size_t)MDIM * KDIM * 2;
    unsigned short* Wc   = (unsigned short*)d_ws;
    unsigned short* comb = (unsigned short*)((char*)d_ws + WC_BYTES);

    convW_kernel<<<256, 256, 0, stream>>>(W1, W2, Wc);
    agg3_kernel<<<512, 256, 0, stream>>>(nodes, neigh, feat, comb);
    gemm_kernel<<<dim3((NB + BN - 1) / BN, MDIM / BM), 256, 0, stream>>>(Wc, comb, out);
}